// Round 5
// baseline (597.593 us; speedup 1.0000x reference)
//
#include <hip/hip_runtime.h>
#include <hip/hip_bf16.h>
#include <stdint.h>

typedef unsigned short u16;
typedef __attribute__((ext_vector_type(8))) __bf16 bf16x8;
typedef __attribute__((ext_vector_type(4))) float f32x4;

#define BATCH 8192
#define HID   2048
#define COMB  4096
#define NTT   128   // K tiles of 32

__device__ __forceinline__ u16 f2bf(float f) {
  uint32_t u = __float_as_uint(f);
  u += 0x7fffu + ((u >> 16) & 1u);
  return (u16)(u >> 16);
}
__device__ __forceinline__ float bf2f(u16 b) {
  return __uint_as_float(((uint32_t)b) << 16);
}
__device__ __forceinline__ float fsigmoid(float x) { return 1.0f / (1.0f + __expf(-x)); }
__device__ __forceinline__ float ftanh(float x) { return 1.0f - 2.0f / (__expf(2.0f * x) + 1.0f); }

__device__ __forceinline__ void gload_lds16(const void* g, void* l) {
  __builtin_amdgcn_global_load_lds(
      (__attribute__((address_space(1))) void*)(uintptr_t)g,
      (__attribute__((address_space(3))) void*)(uintptr_t)l,
      16, 0, 0);
}

#define BARRIER() do { asm volatile("" ::: "memory"); __builtin_amdgcn_s_barrier(); asm volatile("" ::: "memory"); } while (0)
#define VM3()     asm volatile("s_waitcnt vmcnt(3)" ::: "memory")
#define VM0()     asm volatile("s_waitcnt vmcnt(0)" ::: "memory")

// ---- pack [x | h_prev] f32 -> A1 bf16 [8192][4096] ----
__global__ void pack_A_kernel(const float* __restrict__ x, const float* __restrict__ h,
                              u16* __restrict__ A1) {
  const size_t tid = (size_t)blockIdx.x * blockDim.x + threadIdx.x;
  const int r  = (int)(tid >> 9);
  const int c8 = (int)(tid & 511);
  const float* s = (c8 < 256) ? (x + (size_t)r * 2048 + (size_t)c8 * 8)
                              : (h + (size_t)r * 2048 + (size_t)(c8 - 256) * 8);
  const float4 v0 = ((const float4*)s)[0];
  const float4 v1 = ((const float4*)s)[1];
  const uint32_t p0 = (uint32_t)f2bf(v0.x) | ((uint32_t)f2bf(v0.y) << 16);
  const uint32_t p1 = (uint32_t)f2bf(v0.z) | ((uint32_t)f2bf(v0.w) << 16);
  const uint32_t p2 = (uint32_t)f2bf(v1.x) | ((uint32_t)f2bf(v1.y) << 16);
  const uint32_t p3 = (uint32_t)f2bf(v1.z) | ((uint32_t)f2bf(v1.w) << 16);
  *(uint4*)(A1 + tid * 8) = make_uint4(p0, p1, p2, p3);
}

// ---- transpose W [4096][2048] f32 -> dst [2048][4096] bf16 ----
__global__ void transpose_w_kernel(const float* __restrict__ src, u16* __restrict__ dst) {
  __shared__ float tile[32][33];
  const int n0 = blockIdx.x * 32;
  const int k0 = blockIdx.y * 32;
  const int tx = threadIdx.x, ty = threadIdx.y;
#pragma unroll
  for (int i = 0; i < 32; i += 8)
    tile[ty + i][tx] = src[(size_t)(k0 + ty + i) * 2048 + n0 + tx];
  __syncthreads();
#pragma unroll
  for (int i = 0; i < 32; i += 8)
    dst[(size_t)(n0 + ty + i) * 4096 + k0 + tx] = f2bf(tile[tx][ty + i]);
}

// ---- 256x128x32 triple-buffered GEMM, 2 blocks/CU. MODE 0: z|r; MODE 1: n ----
// LDS: A slots 3 x 16KB at 0/16K/32K ; B slots 3 x 8KB at 48K/56K/64K (72KB total)
template <int MODE>
__global__ __launch_bounds__(512, 4) void gemm3b_kernel(
    const u16* __restrict__ A1, const u16* __restrict__ RH,
    const u16* __restrict__ Bt, const float* __restrict__ h_prev,
    const float* __restrict__ bias0, const float* __restrict__ bias1,
    u16* __restrict__ Z, u16* __restrict__ RHout, float* __restrict__ out) {
  extern __shared__ char smem[];
  constexpr int NBN = (MODE == 0) ? 32 : 16;

  const int t = threadIdx.x;
  const int l = t & 63, w = t >> 6;
  const int wm = w >> 1, wn = w & 1;
  const int lr = l & 15, khi = l >> 4;

  const int nwg = 32 * NBN;
  int bid = blockIdx.x;
  bid = (bid & 7) * (nwg >> 3) + (bid >> 3);
  const int bm = bid / NBN, bn = bid % NBN;
  const int arow = bm * 256;
  const int brow = bn * 128;

  // staging coords: thread covers row (w*16 + l/4), 16B granule (l&3); swizzle g^((row>>1)&3)
  const int sr   = l >> 2;                 // 0..15
  const int gsrc = (l & 3) ^ ((sr >> 1) & 3);

  auto stageA = [&](int T, char* slot) {
    const u16* src;
    size_t ld;
    int koff;
    if constexpr (MODE == 1) {
      if (T >= 64) { src = RH; ld = HID;  koff = T * 32 - 2048; }
      else         { src = A1; ld = COMB; koff = T * 32; }
    } else {
      src = A1; ld = COMB; koff = T * 32;
    }
#pragma unroll
    for (int i = 0; i < 2; ++i)
      gload_lds16(src + (size_t)(arow + i * 128 + w * 16 + sr) * ld + koff + gsrc * 8,
                  slot + i * 8192 + w * 1024);
  };
  auto stageB = [&](int T, char* slot) {
    gload_lds16(Bt + (size_t)(brow + w * 16 + sr) * COMB + T * 32 + gsrc * 8,
                slot + w * 1024);
  };

  // lane-constant swizzled read offset: row=16k+lr, k-gran=khi -> byte=row*64+((khi^((lr>>1)&3))<<4)
  const int loff = lr * 64 + ((khi ^ ((lr >> 1) & 3)) << 4);

  char* As0 = smem;          char* As1 = smem + 16384;  char* As2 = smem + 32768;
  char* Bs0 = smem + 49152;  char* Bs1 = smem + 57344;  char* Bs2 = smem + 65536;

  // Prologue: stage tiles 0 and 1; wait tile 0 (leave tile 1's 3 loads in flight)
  stageA(0, As0); stageB(0, Bs0);
  stageA(1, As1); stageB(1, Bs1);
  VM3();
  BARRIER();

  f32x4 acc[4][4] = {};

  for (int j = 0; j < NTT; ++j) {
    // stage tile j+2 into the third slot (its previous contents' reads completed
    // before the end-of-tile-(j-1) barrier; triple-buffer WAR is barrier-certified)
    if (j < NTT - 2) { stageA(j + 2, As2); stageB(j + 2, Bs2); }

    bf16x8 af[4], bb[4];
#pragma unroll
    for (int m = 0; m < 4; ++m)
      af[m] = *(const bf16x8*)(As0 + wm * 4096 + m * 1024 + loff);
#pragma unroll
    for (int n = 0; n < 4; ++n)
      bb[n] = *(const bf16x8*)(Bs0 + wn * 4096 + n * 1024 + loff);

    __builtin_amdgcn_s_setprio(1);
#pragma unroll
    for (int m = 0; m < 4; ++m)
#pragma unroll
      for (int n = 0; n < 4; ++n)
        acc[m][n] = __builtin_amdgcn_mfma_f32_16x16x32_bf16(af[m], bb[n], acc[m][n], 0, 0, 0);
    __builtin_amdgcn_s_setprio(0);

    // counted vmcnt: drains stage(j+1) (issued last tile), leaves stage(j+2) in flight
    if (j < NTT - 2) { VM3(); } else if (j == NTT - 2) { VM0(); }
    if (j < NTT - 1) BARRIER();

    char* ta = As0; As0 = As1; As1 = As2; As2 = ta;
    char* tb = Bs0; Bs0 = Bs1; Bs1 = Bs2; Bs2 = tb;
  }

  // ---- epilogue: wave tile 64x64 at (arow + wm*64, brow-global + wn*64)
  const int r0g = arow + wm * 64 + khi * 4;
  if constexpr (MODE == 0) {
    const bool isZ = (bn < 16);
    const int c0g = bn * 128 + wn * 64 + lr;           // global col in [0,4096)
    const float* bias = isZ ? bias0 : bias1;
#pragma unroll
    for (int n = 0; n < 4; ++n) {
      const int colg = c0g + n * 16;
      const int col = isZ ? colg : (colg - 2048);
      const float bv = bias[col];
#pragma unroll
      for (int m = 0; m < 4; ++m)
#pragma unroll
        for (int r = 0; r < 4; ++r) {
          const int row = r0g + m * 16 + r;
          const size_t idx = (size_t)row * HID + col;
          const float v = acc[m][n][r] + bv;
          if (isZ) {
            Z[idx] = f2bf(fsigmoid(v));
          } else {
            const float rv = fsigmoid(v);
            RHout[idx] = f2bf(rv * h_prev[idx]);
          }
        }
    }
  } else {
    const int c0g = bn * 128 + wn * 64 + lr;           // global col in [0,2048)
#pragma unroll
    for (int n = 0; n < 4; ++n) {
      const int col = c0g + n * 16;
      const float bv = bias0[col];
#pragma unroll
      for (int m = 0; m < 4; ++m)
#pragma unroll
        for (int r = 0; r < 4; ++r) {
          const int row = r0g + m * 16 + r;
          const size_t idx = (size_t)row * HID + col;
          const float nn = ftanh(acc[m][n][r] + bv);
          const float zz = bf2f(Z[idx]);
          const float hp = h_prev[idx];
          out[idx] = (1.0f - zz) * hp + zz * nn;
        }
    }
  }
}

extern "C" void kernel_launch(void* const* d_in, const int* in_sizes, int n_in,
                              void* d_out, int out_size, void* d_ws, size_t ws_size,
                              hipStream_t stream) {
  const float* x  = (const float*)d_in[0];
  const float* h  = (const float*)d_in[1];
  const float* Wz = (const float*)d_in[2];
  const float* bz = (const float*)d_in[3];
  const float* Wr = (const float*)d_in[4];
  const float* br = (const float*)d_in[5];
  const float* Wn = (const float*)d_in[6];
  const float* bn = (const float*)d_in[7];
  float* out = (float*)d_out;

  char* ws = (char*)d_ws;
  u16* A1  = (u16*)(ws);                    // 8192*4096*2 = 67108864
  u16* RH  = (u16*)(ws + 67108864);         // 8192*2048*2 = 33554432
  u16* B1t = (u16*)(ws + 100663296);        // 4096*4096*2 = 33554432  ([Wz;Wr]^T)
  u16* B2t = (u16*)(ws + 134217728);        // 2048*4096*2 = 16777216  (Wn^T)
  u16* Z   = (u16*)(ws + 150994944);        // 8192*2048*2 = 33554432

  (void)hipFuncSetAttribute(reinterpret_cast<const void*>(&gemm3b_kernel<0>),
                            hipFuncAttributeMaxDynamicSharedMemorySize, 73728);
  (void)hipFuncSetAttribute(reinterpret_cast<const void*>(&gemm3b_kernel<1>),
                            hipFuncAttributeMaxDynamicSharedMemorySize, 73728);

  pack_A_kernel<<<16384, 256, 0, stream>>>(x, h, A1);
  dim3 tb(32, 8);
  transpose_w_kernel<<<dim3(64, 128), tb, 0, stream>>>(Wz, B1t);
  transpose_w_kernel<<<dim3(64, 128), tb, 0, stream>>>(Wr, B1t + (size_t)2048 * 4096);
  transpose_w_kernel<<<dim3(64, 128), tb, 0, stream>>>(Wn, B2t);

  gemm3b_kernel<0><<<dim3(1024), 512, 73728, stream>>>(A1, nullptr, B1t, h, bz, br, Z, RH, nullptr);
  gemm3b_kernel<1><<<dim3(512), 512, 73728, stream>>>(A1, RH, B2t, h, bn, nullptr, Z, nullptr, out);
}